// Round 1
// 614.065 us; speedup vs baseline: 1.0814x; 1.0814x over previous
//
#include <hip/hip_runtime.h>
#include <stdint.h>

// Problem constants: x[16,64,256,256] fp32, W[1024,1024] fp32, P=4.
// GEMM view: C[m,n] = sum_k A[m,k] * W[n,k]
//   m = b*4096 + hp*64 + wp   (Hp=Wp=64)
//   k = c*16 + ph*4 + pw
// Tiling: BM=128 (2 hp-rows x 64 wp), BN=128, BK=32 (2 channels), 32 K-iters.

typedef float    f32x4  __attribute__((ext_vector_type(4)));
typedef uint32_t u32x4  __attribute__((ext_vector_type(4)));
typedef __bf16   bf16x8 __attribute__((ext_vector_type(8)));

// Truncate two f32 to bf16 and pack into one u32 (lo in low half).
__device__ __forceinline__ uint32_t pack2(float lo, float hi) {
    return __builtin_amdgcn_perm(__builtin_bit_cast(uint32_t, hi),
                                 __builtin_bit_cast(uint32_t, lo),
                                 0x07060302u);
}

__global__ __launch_bounds__(256, 2)
void patchmix_kernel(const float* __restrict__ x,
                     const float* __restrict__ Wm,
                     float* __restrict__ y) {
    // ---- XCD-aware block swizzle (T1) ----
    // HW dispatch: XCD = blockIdx.x % 8 (round-robin). Give each XCD a
    // contiguous chunk of 64 M-tiles x all 8 N-tiles, N fastest: the 512 KB
    // A strip is fetched once from HBM, then L2-hit by the next 7 blocks on
    // the same XCD. Per-XCD x footprint: 268 MB -> 32 MB.
    const int bx  = blockIdx.x;
    const int xcd = bx & 7;
    const int jj  = bx >> 3;       // 0..511 within this XCD
    const int nt  = jj & 7;        // N-tile fastest -> A-strip temporal reuse in L2
    const int mt  = xcd * 64 + (jj >> 3);   // 0..511
    const int bb  = mt >> 5;       // batch 0..15
    const int hp0 = (mt & 31) << 1;// first of 2 hp rows
    const int n0  = nt << 7;

    const int t    = threadIdx.x;
    const int lane = t & 63;
    const int wave = t >> 6;
    const int wm   = wave >> 1;    // wave row in 2x2 grid
    const int wn   = wave & 1;     // wave col

    // LDS: bf16 tiles in MFMA-fragment order [kq(0..3)][row(0..127)][8 k].
    // Bank-conflict skew: logical (kq, row) lives at kq*128 + (row ^ (kq<<1)).
    // Without it, all four kq sub-tiles alias the same bank quads (2048 B
    // stride), making the B ds_write a 4-way conflict (the 2.5e7 counter).
    __shared__ u32x4 Alds[4 * 128];
    __shared__ u32x4 Blds[4 * 128];

    // ---- A staging geometry (per thread: 2 rounds x 2 rows x float4) ----
    // round r: rp = wave + 4r -> cL = r, hpL = (wave>>1)&1, phh = wave&1
    const int hpL = (wave >> 1) & 1;
    const int phh = wave & 1;
    const float* aBase0 = x + (size_t)bb * (64 * 256 * 256)
                            + ((size_t)(hp0 + hpL) * 4 + 2 * phh) * 256 + lane * 4;
    const int aM = hpL * 64 + lane;          // LDS row (= m_local)
    // kq for round r = 2*r + phh ; skewed row per round:
    const int kqA0 = phh,     kqA1 = 2 + phh;
    const int aM0  = aM ^ (kqA0 << 1);
    const int aM1  = aM ^ (kqA1 << 1);

    // ---- B staging geometry ----
    const int bN  = t >> 2;                  // n_local 0..63 (round0), +64 (round1)
    const int bKq = t & 3;
    const int bNs = bN ^ (bKq << 1);         // skewed row
    const float* bBase0 = Wm + (size_t)(n0 + bN) * 1024 + bKq * 8;

    f32x4 aR[2][2], bR[2][2];

    auto loadAB = [&](int it) {
        const float* a0 = aBase0 + (size_t)(it * 2) * 65536;
        aR[0][0] = *(const f32x4*)(a0);
        aR[0][1] = *(const f32x4*)(a0 + 256);
        aR[1][0] = *(const f32x4*)(a0 + 65536);
        aR[1][1] = *(const f32x4*)(a0 + 65536 + 256);
        const float* b0 = bBase0 + it * 32;
        bR[0][0] = *(const f32x4*)(b0);
        bR[0][1] = *(const f32x4*)(b0 + 4);
        bR[1][0] = *(const f32x4*)(b0 + 65536);   // +64 rows * 1024
        bR[1][1] = *(const f32x4*)(b0 + 65536 + 4);
    };

    f32x4 acc[4][4];
    #pragma unroll
    for (int i = 0; i < 4; ++i)
        #pragma unroll
        for (int j = 0; j < 4; ++j)
            acc[i][j] = (f32x4){0.f, 0.f, 0.f, 0.f};

    loadAB(0);

    const int kg = lane >> 4;   // k-group 0..3
    const int lr = lane & 15;
    const int lrS = lr ^ (kg << 1);   // skewed fragment row (bits 1-2 only; i*16 unaffected)

    for (int it = 0; it < 32; ++it) {
        // pack current staged fp32 -> bf16 (k-order: [row0 pw0..3, row1 pw0..3])
        u32x4 apk0 = (u32x4){ pack2(aR[0][0].x, aR[0][0].y), pack2(aR[0][0].z, aR[0][0].w),
                              pack2(aR[0][1].x, aR[0][1].y), pack2(aR[0][1].z, aR[0][1].w) };
        u32x4 apk1 = (u32x4){ pack2(aR[1][0].x, aR[1][0].y), pack2(aR[1][0].z, aR[1][0].w),
                              pack2(aR[1][1].x, aR[1][1].y), pack2(aR[1][1].z, aR[1][1].w) };
        u32x4 bpk0 = (u32x4){ pack2(bR[0][0].x, bR[0][0].y), pack2(bR[0][0].z, bR[0][0].w),
                              pack2(bR[0][1].x, bR[0][1].y), pack2(bR[0][1].z, bR[0][1].w) };
        u32x4 bpk1 = (u32x4){ pack2(bR[1][0].x, bR[1][0].y), pack2(bR[1][0].z, bR[1][0].w),
                              pack2(bR[1][1].x, bR[1][1].y), pack2(bR[1][1].z, bR[1][1].w) };

        __syncthreads();   // previous iteration's fragment reads done
        Alds[kqA0 * 128 + aM0]      = apk0;      // round0: kq = phh
        Alds[kqA1 * 128 + aM1]      = apk1;      // round1: kq = 2+phh
        Blds[bKq * 128 + bNs]       = bpk0;
        Blds[bKq * 128 + 64 + bNs]  = bpk1;      // (+64 commutes with the XOR skew)
        __syncthreads();   // staging visible

        if (it + 1 < 32) loadAB(it + 1);  // in flight during ds_read + MFMA

        bf16x8 af[4], bfr[4];
        #pragma unroll
        for (int i = 0; i < 4; ++i)
            af[i] = __builtin_bit_cast(bf16x8, Alds[kg * 128 + wm * 64 + i * 16 + lrS]);
        #pragma unroll
        for (int j = 0; j < 4; ++j)
            bfr[j] = __builtin_bit_cast(bf16x8, Blds[kg * 128 + wn * 64 + j * 16 + lrS]);

        #pragma unroll
        for (int i = 0; i < 4; ++i)
            #pragma unroll
            for (int j = 0; j < 4; ++j)
                acc[i][j] = __builtin_amdgcn_mfma_f32_16x16x32_bf16(
                                af[i], bfr[j], acc[i][j], 0, 0, 0);
    }

    // ---- epilogue: fold back to y[b][c][h][w] ----
    // D layout (m89): col n = lane&15, row m = (lane>>4)*4 + reg
    // m_local = wm*64 + i*16 + kg*4 + r  ->  hpL = wm, wp = i*16 + kg*4 + r
    float* yb = y + (size_t)bb * (64 * 256 * 256)
                  + ((size_t)(hp0 + wm) * 4) * 256;
    #pragma unroll
    for (int j = 0; j < 4; ++j) {
        const int ng = n0 + wn * 64 + j * 16 + lr;   // output channel-dim index e
        const int cc = ng >> 4;
        const int ph = (ng >> 2) & 3;
        const int pw = ng & 3;
        float* ybase = yb + ((size_t)cc * 256 + ph) * 256 + pw;
        #pragma unroll
        for (int i = 0; i < 4; ++i) {
            const int wpB = i * 16 + kg * 4;
            #pragma unroll
            for (int r = 0; r < 4; ++r)
                ybase[(size_t)(wpB + r) * 4] = acc[i][j][r];
        }
    }
}

extern "C" void kernel_launch(void* const* d_in, const int* in_sizes, int n_in,
                              void* d_out, int out_size, void* d_ws, size_t ws_size,
                              hipStream_t stream) {
    (void)in_sizes; (void)n_in; (void)d_ws; (void)ws_size; (void)out_size;
    const float* x  = (const float*)d_in[0];
    const float* Wm = (const float*)d_in[1];
    float* y = (float*)d_out;
    // 512 M-tiles x 8 N-tiles, XCD-swizzled inside the kernel
    patchmix_kernel<<<dim3(4096), dim3(256), 0, stream>>>(x, Wm, y);
}